// Round 12
// baseline (1001.406 us; speedup 1.0000x reference)
//
#include <hip/hip_runtime.h>
#include <hip/hip_bf16.h>
#include <stdint.h>
#include <stddef.h>

// Problem constants (GRUTridentDecoder: B=32,H=256,V=512,A=3,NANN=8,DEPTH=7)
#define NB 32
#define NH 256
#define NMID 512      // 2*H
#define NV 512
#define NA 3
#define NDEPTH 7
#define NNODES 3280   // (3^8-1)/2
#define NG 2304       // A*3H
#define MROWS (NNODES * NB)  // 104960
#define HM 64         // fused-head rows per tile (= two nodes); 2 tiles/block

typedef __attribute__((ext_vector_type(8))) short bf16x8;
typedef __attribute__((ext_vector_type(4))) float f32x4;

__device__ __forceinline__ unsigned short f2bf(float x) {
    union { float f; unsigned u; } v; v.f = x;
    unsigned r = v.u + 0x7fffu + ((v.u >> 16) & 1u);
    return (unsigned short)(r >> 16);
}
// packed f32x2 -> bf16x2 (RNE), gfx950 (no builtin; inline asm per T12/m240)
__device__ __forceinline__ unsigned cvt_pk_bf16(float a, float b) {
    unsigned r;
    asm("v_cvt_pk_bf16_f32 %0, %1, %2" : "=v"(r) : "v"(a), "v"(b));
    return r;
}
__device__ __forceinline__ float bf2f(unsigned short u) {
    union { unsigned u; float f; } v; v.u = ((unsigned)u) << 16;
    return v.f;
}
__device__ __forceinline__ float sigm(float x) { return 1.0f / (1.0f + __expf(-x)); }
__device__ __forceinline__ float tanh_(float x) {
    x = fminf(fmaxf(x, -15.0f), 15.0f);
    float e = __expf(2.0f * x);
    return (e - 1.0f) / (e + 1.0f);
}
__device__ __forceinline__ f32x4 splat4(float s) { f32x4 v = {s, s, s, s}; return v; }

__device__ __forceinline__ int preorder_pos(int n) {
    int start = 0, cnt = 1, l = 0;
    while (n >= start + cnt) { start += cnt; cnt *= 3; l++; }
    int p = n - start;
    int pw = 1;
    for (int j = 0; j < l - 1; j++) pw *= 3;
    int pos = 0;
    for (int k = 1; k <= l; k++) {
        int d = (p / pw) % 3;
        int e = NDEPTH - k + 1;
        int p3 = 1; for (int j = 0; j < e; j++) p3 *= 3;
        pos += 1 + d * ((p3 - 1) / 2);
        pw /= 3;
    }
    return pos;
}

// ---- prep (single kernel): weight casts + gx_t + root init + posmap
__global__ void prep_all(const float* __restrict__ root, const float* __restrict__ ann_table,
                         const int* __restrict__ ann_ids,
                         const float* __restrict__ w_ih, const float* __restrict__ b_ih,
                         const float* __restrict__ whh_f, const float* __restrict__ w1_f,
                         const float* __restrict__ w2_f,
                         unsigned short* __restrict__ whh_b, unsigned short* __restrict__ w1_b,
                         unsigned short* __restrict__ w2_b,
                         float* __restrict__ gx_t, int* __restrict__ posmap,
                         unsigned short* __restrict__ hid_b) {
    int gtid = blockIdx.x * blockDim.x + threadIdx.x;
    int nth = gridDim.x * blockDim.x;
    const int n_whh = NG * NH, n_w1 = NMID * NH, n_w2 = NV * NMID;
    const int total = n_whh + n_w1 + n_w2;
    for (int i = gtid; i < total; i += nth) {
        if (i < n_whh) whh_b[i] = f2bf(whh_f[i]);
        else if (i < n_whh + n_w1) w1_b[i - n_whh] = f2bf(w1_f[i - n_whh]);
        else w2_b[i - n_whh - n_w1] = f2bf(w2_f[i - n_whh - n_w1]);
    }
    if (gtid < NB * NH) hid_b[gtid] = f2bf(root[gtid]);
    if (gtid < NNODES) posmap[gtid] = preorder_pos(gtid);
    int lane = threadIdx.x & 63;
    int gw = gtid >> 6;
    int nw = nth >> 6;
    for (int e = gw; e < NB * NG; e += nw) {
        int b = e / NG;
        int col = e - b * NG;
        const float* xr = ann_table + (size_t)ann_ids[b] * NH;
        const float* wr = w_ih + (size_t)col * NH;
        float4 xv = *(const float4*)(xr + lane * 4);
        float4 wv = *(const float4*)(wr + lane * 4);
        float s = xv.x * wv.x + xv.y * wv.y + xv.z * wv.z + xv.w * wv.w;
        #pragma unroll
        for (int off = 32; off; off >>= 1) s += __shfl_down(s, off);
        if (lane == 0) gx_t[(size_t)col * NB + b] = s + b_ih[col];
    }
}

// ---- GRU level: NPB nodes per blockIdx.x (M = 32*NPB rows); 6 column-splits
// across blockIdx.y; wave wv owns 16 flat (a,h') cols, all 3 gates, all M rows.
template<int NPB>
__global__ __launch_bounds__(512, 2)
void gru_level(const unsigned short* __restrict__ hid_b_in,
               unsigned short* __restrict__ hid_b_out,
               const unsigned short* __restrict__ whh_b,
               const float* __restrict__ b_hh, const float* __restrict__ gx_t,
               int start, int child_start, int cnt) {
    constexpr int M = 32 * NPB;
    __shared__ char a_s[M * 512];   // M rows x 256 bf16, swizzled (row&15)<<4

    int tid = threadIdx.x;
    int lane = tid & 63;
    int wv = tid >> 6;
    int lr = lane & 15;
    int kg = (lane >> 4) * 8;
    int rbase = (lane >> 4) * 4;
    int nrel0 = blockIdx.x * NPB;
    size_t prow0 = (size_t)(start + nrel0) * NB;

    for (int c = tid; c < M * 32; c += 512) {
        int row = c >> 5;
        int coloff = (c & 31) * 8;
        bf16x8 v = *(const bf16x8*)(hid_b_in + (prow0 + row) * NH + coloff);
        *(bf16x8*)(a_s + ((row * 512 + coloff * 2) ^ ((row & 15) << 4))) = v;
    }
    __syncthreads();

    int Gb = (blockIdx.y * 8 + wv) * 16;   // flat col = a*256 + h'
    int a = Gb >> 8;
    int colh = (Gb & 255) + lr;
    int gcol = a * 768 + colh;
    const unsigned short* bptr = whh_b + (size_t)(a * 512 + Gb + lr) * NH + kg;

    float bhr = b_hh[gcol], bhz = b_hh[gcol + 256], bhn = b_hh[gcol + 512];

    f32x4 acc[3][2 * NPB];
    #pragma unroll
    for (int g = 0; g < 2; ++g) {
        f32x4 gr = *(const f32x4*)(gx_t + (size_t)gcol * NB + g * 16 + rbase);
        f32x4 gz = *(const f32x4*)(gx_t + (size_t)(gcol + 256) * NB + g * 16 + rbase);
        #pragma unroll
        for (int mi = g; mi < 2 * NPB; mi += 2) {
            acc[0][mi] = gr + splat4(bhr);
            acc[1][mi] = gz + splat4(bhz);
            acc[2][mi] = splat4(bhn);
        }
    }

    bf16x8 bcur[3];
    #pragma unroll
    for (int t = 0; t < 3; ++t) bcur[t] = *(const bf16x8*)(bptr + t * 256 * NH);
    #pragma unroll
    for (int k0 = 0; k0 < NH; k0 += 32) {
        bf16x8 bnxt[3];
        if (k0 + 32 < NH) {
            #pragma unroll
            for (int t = 0; t < 3; ++t) bnxt[t] = *(const bf16x8*)(bptr + t * 256 * NH + k0 + 32);
        }
        bf16x8 af[2 * NPB];
        #pragma unroll
        for (int mi = 0; mi < 2 * NPB; ++mi) {
            int row = mi * 16 + lr;
            af[mi] = *(const bf16x8*)(a_s + ((row * 512 + (k0 + kg) * 2) ^ ((row & 15) << 4)));
        }
        __builtin_amdgcn_s_setprio(1);
        #pragma unroll
        for (int t = 0; t < 3; ++t)
            #pragma unroll
            for (int mi = 0; mi < 2 * NPB; ++mi)
                acc[t][mi] = __builtin_amdgcn_mfma_f32_16x16x32_bf16(af[mi], bcur[t], acc[t][mi], 0, 0, 0);
        __builtin_amdgcn_s_setprio(0);
        if (k0 + 32 < NH) {
            #pragma unroll
            for (int t = 0; t < 3; ++t) bcur[t] = bnxt[t];
        }
    }

    f32x4 gxn[2];
    #pragma unroll
    for (int g = 0; g < 2; ++g)
        gxn[g] = *(const f32x4*)(gx_t + (size_t)(gcol + 512) * NB + g * 16 + rbase);
    #pragma unroll
    for (int mi = 0; mi < 2 * NPB; ++mi) {
        int ns = (mi * 16 + rbase) >> 5;
        if (nrel0 + ns >= cnt) continue;
        size_t crow = ((size_t)(child_start + (nrel0 + ns) * 3 + a)) * NB;
        float hnew[4];
        #pragma unroll
        for (int j = 0; j < 4; ++j) {
            int row = mi * 16 + rbase + j;
            float r = sigm(acc[0][mi][j]);
            float z = sigm(acc[1][mi][j]);
            float nn = tanh_(gxn[mi & 1][j] + r * acc[2][mi][j]);
            unsigned short hpu = *(const unsigned short*)(a_s + ((row * 512 + colh * 2) ^ ((row & 15) << 4)));
            hnew[j] = (1.0f - z) * nn + z * bf2f(hpu);
        }
        unsigned u01 = cvt_pk_bf16(hnew[0], hnew[1]);
        unsigned u23 = cvt_pk_bf16(hnew[2], hnew[3]);
        int b0 = (mi * 16 + rbase) & 31;
        hid_b_out[(crow + b0 + 0) * NH + colh] = (unsigned short)u01;
        hid_b_out[(crow + b0 + 1) * NH + colh] = (unsigned short)(u01 >> 16);
        hid_b_out[(crow + b0 + 2) * NH + colh] = (unsigned short)u23;
        hid_b_out[(crow + b0 + 3) * NH + colh] = (unsigned short)(u23 >> 16);
    }
}

// ---- fused head: 2 tiles of HM=64 rows per block (grid 820). Cross-tile
// software pipeline: tile-1 A-loads issued after tile-0 phase 1 (T14 split),
// written to LDS after tile-0 phase 2. setprio around MFMA clusters (T5).
__global__ __launch_bounds__(512, 4)
void head_fused(const unsigned short* __restrict__ hid_b,
                const unsigned short* __restrict__ w1_b, const float* __restrict__ b1,
                const unsigned short* __restrict__ w2_b, const float* __restrict__ b2,
                const int* __restrict__ posmap, float* __restrict__ out) {
    __shared__ char smem[HM * NMID * 2];  // 64 KB: A-tile (32KB) overlaid by mid (64KB)

    int tid = threadIdx.x;
    int lane = tid & 63;
    int wv = tid >> 6;
    int mbase0 = blockIdx.x * 2 * HM;
    int lr = lane & 15;
    int kg = (lane >> 4) * 8;
    int rbase = (lane >> 4) * 4;
    int n0w = wv * 64;

    const unsigned short* bbase1 = w1_b + ((size_t)(n0w + lr)) * NH + kg;
    const unsigned short* bbase2 = w2_b + ((size_t)(n0w + lr)) * NMID + kg;
    float bv1 = b1[n0w + (lane & 15)];  // placeholder to keep b1 hot; real loads below

    // initial stage: tile-0 A (64 x 256 bf16) swizzled
    #pragma unroll
    for (int i = 0; i < 4; ++i) {
        int c = tid + i * 512;
        int row = c >> 5;
        int coloff = (c & 31) * 8;
        bf16x8 v = *(const bf16x8*)(hid_b + ((size_t)(mbase0 + row)) * NH + coloff);
        *(bf16x8*)(smem + ((row * 512 + coloff * 2) ^ ((row & 15) << 4))) = v;
    }
    __syncthreads();

    bf16x8 areg[4];

    for (int t = 0; t < 2; ++t) {
        int mbase = mbase0 + t * HM;

        f32x4 acc[4][4];
        #pragma unroll
        for (int mi = 0; mi < 4; ++mi)
            #pragma unroll
            for (int ni = 0; ni < 4; ++ni) acc[mi][ni] = (f32x4){0.f, 0.f, 0.f, 0.f};

        // ---- phase 1: mid = sigmoid(A @ w1^T + b1)
        {
            bf16x8 bcur[4];
            #pragma unroll
            for (int ni = 0; ni < 4; ++ni) bcur[ni] = *(const bf16x8*)(bbase1 + ni * 16 * NH);
            #pragma unroll
            for (int k0 = 0; k0 < NH; k0 += 32) {
                bf16x8 bnxt[4];
                if (k0 + 32 < NH) {
                    #pragma unroll
                    for (int ni = 0; ni < 4; ++ni) bnxt[ni] = *(const bf16x8*)(bbase1 + ni * 16 * NH + k0 + 32);
                }
                bf16x8 af[4];
                #pragma unroll
                for (int mi = 0; mi < 4; ++mi) {
                    int row = mi * 16 + lr;
                    af[mi] = *(const bf16x8*)(smem + ((row * 512 + (k0 + kg) * 2) ^ ((row & 15) << 4)));
                }
                __builtin_amdgcn_s_setprio(1);
                #pragma unroll
                for (int mi = 0; mi < 4; ++mi)
                    #pragma unroll
                    for (int ni = 0; ni < 4; ++ni)
                        acc[mi][ni] = __builtin_amdgcn_mfma_f32_16x16x32_bf16(af[mi], bcur[ni], acc[mi][ni], 0, 0, 0);
                __builtin_amdgcn_s_setprio(0);
                if (k0 + 32 < NH) {
                    #pragma unroll
                    for (int ni = 0; ni < 4; ++ni) bcur[ni] = bnxt[ni];
                }
            }
        }

        // T14 issue-early: tile-1 A-loads into regs while tile-0 continues
        if (t == 0) {
            #pragma unroll
            for (int i = 0; i < 4; ++i) {
                int c = tid + i * 512;
                int row = c >> 5;
                int coloff = (c & 31) * 8;
                areg[i] = *(const bf16x8*)(hid_b + ((size_t)(mbase0 + HM + row)) * NH + coloff);
            }
        }
        __syncthreads();   // all A reads done before mid overwrites the region

        // epilogue 1: sigmoid -> cvt_pk bf16 -> LDS (1024B rows)
        #pragma unroll
        for (int mi = 0; mi < 4; ++mi)
            #pragma unroll
            for (int ni = 0; ni < 4; ++ni) {
                int col = n0w + ni * 16 + lr;
                float bv = b1[col];
                float v0 = sigm(acc[mi][ni][0] + bv);
                float v1 = sigm(acc[mi][ni][1] + bv);
                float v2 = sigm(acc[mi][ni][2] + bv);
                float v3 = sigm(acc[mi][ni][3] + bv);
                unsigned u01 = cvt_pk_bf16(v0, v1);
                unsigned u23 = cvt_pk_bf16(v2, v3);
                int r0 = mi * 16 + rbase;
                *(unsigned short*)(smem + (((r0 + 0) * 1024 + col * 2) ^ (((r0 + 0) & 15) << 4))) = (unsigned short)u01;
                *(unsigned short*)(smem + (((r0 + 1) * 1024 + col * 2) ^ (((r0 + 1) & 15) << 4))) = (unsigned short)(u01 >> 16);
                *(unsigned short*)(smem + (((r0 + 2) * 1024 + col * 2) ^ (((r0 + 2) & 15) << 4))) = (unsigned short)u23;
                *(unsigned short*)(smem + (((r0 + 3) * 1024 + col * 2) ^ (((r0 + 3) & 15) << 4))) = (unsigned short)(u23 >> 16);
            }
        __syncthreads();

        // ---- phase 2: out = mid @ w2^T + b2
        #pragma unroll
        for (int mi = 0; mi < 4; ++mi)
            #pragma unroll
            for (int ni = 0; ni < 4; ++ni) acc[mi][ni] = (f32x4){0.f, 0.f, 0.f, 0.f};
        {
            bf16x8 bcur[4];
            #pragma unroll
            for (int ni = 0; ni < 4; ++ni) bcur[ni] = *(const bf16x8*)(bbase2 + ni * 16 * NMID);
            #pragma unroll
            for (int k0 = 0; k0 < NMID; k0 += 32) {
                bf16x8 bnxt[4];
                if (k0 + 32 < NMID) {
                    #pragma unroll
                    for (int ni = 0; ni < 4; ++ni) bnxt[ni] = *(const bf16x8*)(bbase2 + ni * 16 * NMID + k0 + 32);
                }
                bf16x8 af[4];
                #pragma unroll
                for (int mi = 0; mi < 4; ++mi) {
                    int row = mi * 16 + lr;
                    af[mi] = *(const bf16x8*)(smem + ((row * 1024 + (k0 + kg) * 2) ^ ((row & 15) << 4)));
                }
                __builtin_amdgcn_s_setprio(1);
                #pragma unroll
                for (int mi = 0; mi < 4; ++mi)
                    #pragma unroll
                    for (int ni = 0; ni < 4; ++ni)
                        acc[mi][ni] = __builtin_amdgcn_mfma_f32_16x16x32_bf16(af[mi], bcur[ni], acc[mi][ni], 0, 0, 0);
                __builtin_amdgcn_s_setprio(0);
                if (k0 + 32 < NMID) {
                    #pragma unroll
                    for (int ni = 0; ni < 4; ++ni) bcur[ni] = bnxt[ni];
                }
            }
        }
        __syncthreads();   // mid reads done; smem free for tile-1 A

        // T14 write-late: staged tile-1 A into LDS (overlapped with stores below)
        if (t == 0) {
            #pragma unroll
            for (int i = 0; i < 4; ++i) {
                int c = tid + i * 512;
                int row = c >> 5;
                int coloff = (c & 31) * 8;
                *(bf16x8*)(smem + ((row * 512 + coloff * 2) ^ ((row & 15) << 4))) = areg[i];
            }
        }

        // epilogue 2: bias + permuted store (scalar, hoisted row pointers)
        float bv4[4];
        #pragma unroll
        for (int ni = 0; ni < 4; ++ni) bv4[ni] = b2[n0w + ni * 16 + lr];
        #pragma unroll
        for (int mi = 0; mi < 4; ++mi) {
            int row0 = mbase + mi * 16 + rbase;
            #pragma unroll
            for (int j = 0; j < 4; ++j) {
                int row = row0 + j;
                int b = row & 31;
                int node = row >> 5;
                float* orow = out + ((size_t)posmap[node] * NB + b) * NV + n0w + lr;
                #pragma unroll
                for (int ni = 0; ni < 4; ++ni)
                    orow[ni * 16] = acc[mi][ni][j] + bv4[ni];
            }
        }
        if (t == 0) __syncthreads();   // tile-1 A visible to all waves
    }
    (void)bv1;
}

extern "C" void kernel_launch(void* const* d_in, const int* in_sizes, int n_in,
                              void* d_out, int out_size, void* d_ws, size_t ws_size,
                              hipStream_t stream) {
    const float* root      = (const float*)d_in[0];
    const float* ann_table = (const float*)d_in[1];
    const float* w1        = (const float*)d_in[2];
    const float* b1        = (const float*)d_in[3];
    const float* w2        = (const float*)d_in[4];
    const float* b2        = (const float*)d_in[5];
    const float* w_ih      = (const float*)d_in[6];
    const float* w_hh      = (const float*)d_in[7];
    const float* b_ih      = (const float*)d_in[8];
    const float* b_hh      = (const float*)d_in[9];
    const int*   ann_ids   = (const int*)d_in[10];

    uint8_t* ws = (uint8_t*)d_ws;
    unsigned short* whh_b = (unsigned short*)ws; ws += (size_t)NG * NH * 2;
    unsigned short* w1_b  = (unsigned short*)ws; ws += (size_t)NMID * NH * 2;
    unsigned short* w2_b  = (unsigned short*)ws; ws += (size_t)NV * NMID * 2;
    float* gx_t           = (float*)ws;          ws += (size_t)NB * NG * 4;
    int* posmap           = (int*)ws;            ws += (size_t)NNODES * 4;
    unsigned short* hid_b = (unsigned short*)ws; ws += (size_t)NNODES * NB * NH * 2;

    prep_all<<<1024, 256, 0, stream>>>(root, ann_table, ann_ids, w_ih, b_ih,
                                       w_hh, w1, w2, whh_b, w1_b, w2_b,
                                       gx_t, posmap, hid_b);

    int start = 0, cnt = 1;
    for (int l = 0; l < NDEPTH; ++l) {
        int child_start = start + cnt;
        if (cnt >= 729) {
            gru_level<4><<<dim3((cnt + 3) / 4, 6), 512, 0, stream>>>(
                hid_b, hid_b, whh_b, b_hh, gx_t, start, child_start, cnt);
        } else if (cnt >= 128) {
            gru_level<2><<<dim3((cnt + 1) / 2, 6), 512, 0, stream>>>(
                hid_b, hid_b, whh_b, b_hh, gx_t, start, child_start, cnt);
        } else {
            gru_level<1><<<dim3(cnt, 6), 512, 0, stream>>>(
                hid_b, hid_b, whh_b, b_hh, gx_t, start, child_start, cnt);
        }
        start = child_start; cnt *= 3;
    }
    head_fused<<<MROWS / (2 * HM), 512, 0, stream>>>(hid_b, w1_b, b1, w2_b, b2, posmap, (float*)d_out);
}

// Round 13
// 365.749 us; speedup vs baseline: 2.7380x; 2.7380x over previous
//
#include <hip/hip_runtime.h>
#include <hip/hip_bf16.h>
#include <stdint.h>
#include <stddef.h>

// Problem constants (GRUTridentDecoder: B=32,H=256,V=512,A=3,NANN=8,DEPTH=7)
#define NB 32
#define NH 256
#define NMID 512      // 2*H
#define NV 512
#define NA 3
#define NDEPTH 7
#define NNODES 3280   // (3^8-1)/2
#define NG 2304       // A*3H
#define MROWS (NNODES * NB)  // 104960
#define HM 64         // fused-head rows per block (= two nodes)

typedef __attribute__((ext_vector_type(8))) short bf16x8;
typedef __attribute__((ext_vector_type(4))) float f32x4;

__device__ __forceinline__ unsigned short f2bf(float x) {
    union { float f; unsigned u; } v; v.f = x;
    unsigned r = v.u + 0x7fffu + ((v.u >> 16) & 1u);
    return (unsigned short)(r >> 16);
}
// packed f32x2 -> bf16x2 (RNE), gfx950 (no builtin; inline asm per T12/m240)
__device__ __forceinline__ unsigned cvt_pk_bf16(float a, float b) {
    unsigned r;
    asm("v_cvt_pk_bf16_f32 %0, %1, %2" : "=v"(r) : "v"(a), "v"(b));
    return r;
}
__device__ __forceinline__ float bf2f(unsigned short u) {
    union { unsigned u; float f; } v; v.u = ((unsigned)u) << 16;
    return v.f;
}
__device__ __forceinline__ float sigm(float x) { return 1.0f / (1.0f + __expf(-x)); }
__device__ __forceinline__ float tanh_(float x) {
    x = fminf(fmaxf(x, -15.0f), 15.0f);
    float e = __expf(2.0f * x);
    return (e - 1.0f) / (e + 1.0f);
}
__device__ __forceinline__ f32x4 splat4(float s) { f32x4 v = {s, s, s, s}; return v; }

__device__ __forceinline__ int preorder_pos(int n) {
    int start = 0, cnt = 1, l = 0;
    while (n >= start + cnt) { start += cnt; cnt *= 3; l++; }
    int p = n - start;
    int pw = 1;
    for (int j = 0; j < l - 1; j++) pw *= 3;
    int pos = 0;
    for (int k = 1; k <= l; k++) {
        int d = (p / pw) % 3;
        int e = NDEPTH - k + 1;
        int p3 = 1; for (int j = 0; j < e; j++) p3 *= 3;
        pos += 1 + d * ((p3 - 1) / 2);
        pw /= 3;
    }
    return pos;
}

// ---- prep (single kernel): weight casts + gx_t + root init + posmap
__global__ void prep_all(const float* __restrict__ root, const float* __restrict__ ann_table,
                         const int* __restrict__ ann_ids,
                         const float* __restrict__ w_ih, const float* __restrict__ b_ih,
                         const float* __restrict__ whh_f, const float* __restrict__ w1_f,
                         const float* __restrict__ w2_f,
                         unsigned short* __restrict__ whh_b, unsigned short* __restrict__ w1_b,
                         unsigned short* __restrict__ w2_b,
                         float* __restrict__ gx_t, int* __restrict__ posmap,
                         unsigned short* __restrict__ hid_b) {
    int gtid = blockIdx.x * blockDim.x + threadIdx.x;
    int nth = gridDim.x * blockDim.x;
    const int n_whh = NG * NH, n_w1 = NMID * NH, n_w2 = NV * NMID;
    const int total = n_whh + n_w1 + n_w2;
    for (int i = gtid; i < total; i += nth) {
        if (i < n_whh) whh_b[i] = f2bf(whh_f[i]);
        else if (i < n_whh + n_w1) w1_b[i - n_whh] = f2bf(w1_f[i - n_whh]);
        else w2_b[i - n_whh - n_w1] = f2bf(w2_f[i - n_whh - n_w1]);
    }
    if (gtid < NB * NH) hid_b[gtid] = f2bf(root[gtid]);
    if (gtid < NNODES) posmap[gtid] = preorder_pos(gtid);
    int lane = threadIdx.x & 63;
    int gw = gtid >> 6;
    int nw = nth >> 6;
    for (int e = gw; e < NB * NG; e += nw) {
        int b = e / NG;
        int col = e - b * NG;
        const float* xr = ann_table + (size_t)ann_ids[b] * NH;
        const float* wr = w_ih + (size_t)col * NH;
        float4 xv = *(const float4*)(xr + lane * 4);
        float4 wv = *(const float4*)(wr + lane * 4);
        float s = xv.x * wv.x + xv.y * wv.y + xv.z * wv.z + xv.w * wv.w;
        #pragma unroll
        for (int off = 32; off; off >>= 1) s += __shfl_down(s, off);
        if (lane == 0) gx_t[(size_t)col * NB + b] = s + b_ih[col];
    }
}

// ---- GRU level: NPB nodes per blockIdx.x (M = 32*NPB rows); 6 column-splits
// across blockIdx.y; wave wv owns 16 flat (a,h') cols, all 3 gates, all M rows.
template<int NPB>
__global__ __launch_bounds__(512, 2)
void gru_level(const unsigned short* __restrict__ hid_b_in,
               unsigned short* __restrict__ hid_b_out,
               const unsigned short* __restrict__ whh_b,
               const float* __restrict__ b_hh, const float* __restrict__ gx_t,
               int start, int child_start, int cnt) {
    constexpr int M = 32 * NPB;
    __shared__ char a_s[M * 512];   // M rows x 256 bf16, swizzled (row&15)<<4

    int tid = threadIdx.x;
    int lane = tid & 63;
    int wv = tid >> 6;
    int lr = lane & 15;
    int kg = (lane >> 4) * 8;
    int rbase = (lane >> 4) * 4;
    int nrel0 = blockIdx.x * NPB;
    size_t prow0 = (size_t)(start + nrel0) * NB;

    for (int c = tid; c < M * 32; c += 512) {
        int row = c >> 5;
        int coloff = (c & 31) * 8;
        bf16x8 v = *(const bf16x8*)(hid_b_in + (prow0 + row) * NH + coloff);
        *(bf16x8*)(a_s + ((row * 512 + coloff * 2) ^ ((row & 15) << 4))) = v;
    }
    __syncthreads();

    int Gb = (blockIdx.y * 8 + wv) * 16;   // flat col = a*256 + h'
    int a = Gb >> 8;
    int colh = (Gb & 255) + lr;
    int gcol = a * 768 + colh;
    const unsigned short* bptr = whh_b + (size_t)(a * 512 + Gb + lr) * NH + kg;

    float bhr = b_hh[gcol], bhz = b_hh[gcol + 256], bhn = b_hh[gcol + 512];

    f32x4 acc[3][2 * NPB];
    #pragma unroll
    for (int g = 0; g < 2; ++g) {
        f32x4 gr = *(const f32x4*)(gx_t + (size_t)gcol * NB + g * 16 + rbase);
        f32x4 gz = *(const f32x4*)(gx_t + (size_t)(gcol + 256) * NB + g * 16 + rbase);
        #pragma unroll
        for (int mi = g; mi < 2 * NPB; mi += 2) {
            acc[0][mi] = gr + splat4(bhr);
            acc[1][mi] = gz + splat4(bhz);
            acc[2][mi] = splat4(bhn);
        }
    }

    bf16x8 bcur[3];
    #pragma unroll
    for (int t = 0; t < 3; ++t) bcur[t] = *(const bf16x8*)(bptr + t * 256 * NH);
    #pragma unroll
    for (int k0 = 0; k0 < NH; k0 += 32) {
        bf16x8 bnxt[3];
        if (k0 + 32 < NH) {
            #pragma unroll
            for (int t = 0; t < 3; ++t) bnxt[t] = *(const bf16x8*)(bptr + t * 256 * NH + k0 + 32);
        }
        bf16x8 af[2 * NPB];
        #pragma unroll
        for (int mi = 0; mi < 2 * NPB; ++mi) {
            int row = mi * 16 + lr;
            af[mi] = *(const bf16x8*)(a_s + ((row * 512 + (k0 + kg) * 2) ^ ((row & 15) << 4)));
        }
        __builtin_amdgcn_s_setprio(1);
        #pragma unroll
        for (int t = 0; t < 3; ++t)
            #pragma unroll
            for (int mi = 0; mi < 2 * NPB; ++mi)
                acc[t][mi] = __builtin_amdgcn_mfma_f32_16x16x32_bf16(af[mi], bcur[t], acc[t][mi], 0, 0, 0);
        __builtin_amdgcn_s_setprio(0);
        if (k0 + 32 < NH) {
            #pragma unroll
            for (int t = 0; t < 3; ++t) bcur[t] = bnxt[t];
        }
    }

    f32x4 gxn[2];
    #pragma unroll
    for (int g = 0; g < 2; ++g)
        gxn[g] = *(const f32x4*)(gx_t + (size_t)(gcol + 512) * NB + g * 16 + rbase);
    #pragma unroll
    for (int mi = 0; mi < 2 * NPB; ++mi) {
        int ns = (mi * 16 + rbase) >> 5;
        if (nrel0 + ns >= cnt) continue;
        size_t crow = ((size_t)(child_start + (nrel0 + ns) * 3 + a)) * NB;
        float hnew[4];
        #pragma unroll
        for (int j = 0; j < 4; ++j) {
            int row = mi * 16 + rbase + j;
            float r = sigm(acc[0][mi][j]);
            float z = sigm(acc[1][mi][j]);
            float nn = tanh_(gxn[mi & 1][j] + r * acc[2][mi][j]);
            unsigned short hpu = *(const unsigned short*)(a_s + ((row * 512 + colh * 2) ^ ((row & 15) << 4)));
            hnew[j] = (1.0f - z) * nn + z * bf2f(hpu);
        }
        unsigned u01 = cvt_pk_bf16(hnew[0], hnew[1]);
        unsigned u23 = cvt_pk_bf16(hnew[2], hnew[3]);
        int b0 = (mi * 16 + rbase) & 31;
        hid_b_out[(crow + b0 + 0) * NH + colh] = (unsigned short)u01;
        hid_b_out[(crow + b0 + 1) * NH + colh] = (unsigned short)(u01 >> 16);
        hid_b_out[(crow + b0 + 2) * NH + colh] = (unsigned short)u23;
        hid_b_out[(crow + b0 + 3) * NH + colh] = (unsigned short)(u23 >> 16);
    }
}

// ---- fused head (R9 exact, best measured 195 µs): HM=64, 8 waves, wave owns
// 64 cols x 64 rows. A staged in swizzled LDS (overlaid by mid); B depth-1 dbuf.
__global__ __launch_bounds__(512, 4)
void head_fused(const unsigned short* __restrict__ hid_b,
                const unsigned short* __restrict__ w1_b, const float* __restrict__ b1,
                const unsigned short* __restrict__ w2_b, const float* __restrict__ b2,
                const int* __restrict__ posmap, float* __restrict__ out) {
    __shared__ char smem[HM * NMID * 2];  // 64 KB: A-tile (32KB) then mid (64KB)

    int tid = threadIdx.x;
    int lane = tid & 63;
    int wv = tid >> 6;
    int mbase = blockIdx.x * HM;
    int lr = lane & 15;
    int kg = (lane >> 4) * 8;
    int rbase = (lane >> 4) * 4;
    int n0w = wv * 64;

    // stage A (64 x 256 bf16, 512B rows) swizzled
    for (int c = tid; c < HM * 32; c += 512) {
        int row = c >> 5;
        int coloff = (c & 31) * 8;
        bf16x8 v = *(const bf16x8*)(hid_b + ((size_t)(mbase + row)) * NH + coloff);
        *(bf16x8*)(smem + ((row * 512 + coloff * 2) ^ ((row & 15) << 4))) = v;
    }
    __syncthreads();

    f32x4 acc[4][4];
    #pragma unroll
    for (int mi = 0; mi < 4; ++mi)
        #pragma unroll
        for (int ni = 0; ni < 4; ++ni) acc[mi][ni] = (f32x4){0.f, 0.f, 0.f, 0.f};

    // ---- phase 1: mid = sigmoid(A @ w1^T + b1); A from LDS, B dbuf from L2
    {
        const unsigned short* bbase = w1_b + ((size_t)(n0w + lr)) * NH + kg;
        bf16x8 bcur[4];
        #pragma unroll
        for (int ni = 0; ni < 4; ++ni) bcur[ni] = *(const bf16x8*)(bbase + ni * 16 * NH);
        #pragma unroll
        for (int k0 = 0; k0 < NH; k0 += 32) {
            bf16x8 bnxt[4];
            if (k0 + 32 < NH) {
                #pragma unroll
                for (int ni = 0; ni < 4; ++ni) bnxt[ni] = *(const bf16x8*)(bbase + ni * 16 * NH + k0 + 32);
            }
            bf16x8 af[4];
            #pragma unroll
            for (int mi = 0; mi < 4; ++mi) {
                int row = mi * 16 + lr;
                af[mi] = *(const bf16x8*)(smem + ((row * 512 + (k0 + kg) * 2) ^ ((row & 15) << 4)));
            }
            #pragma unroll
            for (int mi = 0; mi < 4; ++mi)
                #pragma unroll
                for (int ni = 0; ni < 4; ++ni)
                    acc[mi][ni] = __builtin_amdgcn_mfma_f32_16x16x32_bf16(af[mi], bcur[ni], acc[mi][ni], 0, 0, 0);
            if (k0 + 32 < NH) {
                #pragma unroll
                for (int ni = 0; ni < 4; ++ni) bcur[ni] = bnxt[ni];
            }
        }
    }
    __syncthreads();   // all A reads done before mid overwrites the region

    // epilogue 1: sigmoid -> cvt_pk bf16 -> LDS (1024B rows, swizzle (row&15)<<4)
    #pragma unroll
    for (int mi = 0; mi < 4; ++mi)
        #pragma unroll
        for (int ni = 0; ni < 4; ++ni) {
            int col = n0w + ni * 16 + lr;
            float bv = b1[col];
            float v0 = sigm(acc[mi][ni][0] + bv);
            float v1 = sigm(acc[mi][ni][1] + bv);
            float v2 = sigm(acc[mi][ni][2] + bv);
            float v3 = sigm(acc[mi][ni][3] + bv);
            unsigned u01 = cvt_pk_bf16(v0, v1);
            unsigned u23 = cvt_pk_bf16(v2, v3);
            int r0 = mi * 16 + rbase;
            *(unsigned short*)(smem + (((r0 + 0) * 1024 + col * 2) ^ (((r0 + 0) & 15) << 4))) = (unsigned short)u01;
            *(unsigned short*)(smem + (((r0 + 1) * 1024 + col * 2) ^ (((r0 + 1) & 15) << 4))) = (unsigned short)(u01 >> 16);
            *(unsigned short*)(smem + (((r0 + 2) * 1024 + col * 2) ^ (((r0 + 2) & 15) << 4))) = (unsigned short)u23;
            *(unsigned short*)(smem + (((r0 + 3) * 1024 + col * 2) ^ (((r0 + 3) & 15) << 4))) = (unsigned short)(u23 >> 16);
        }
    __syncthreads();

    // ---- phase 2: out = mid @ w2^T + b2; K=512, depth-1 dbuf
    #pragma unroll
    for (int mi = 0; mi < 4; ++mi)
        #pragma unroll
        for (int ni = 0; ni < 4; ++ni) acc[mi][ni] = (f32x4){0.f, 0.f, 0.f, 0.f};
    {
        const unsigned short* bbase = w2_b + ((size_t)(n0w + lr)) * NMID + kg;
        bf16x8 bcur[4];
        #pragma unroll
        for (int ni = 0; ni < 4; ++ni) bcur[ni] = *(const bf16x8*)(bbase + ni * 16 * NMID);
        #pragma unroll
        for (int k0 = 0; k0 < NMID; k0 += 32) {
            bf16x8 bnxt[4];
            if (k0 + 32 < NMID) {
                #pragma unroll
                for (int ni = 0; ni < 4; ++ni) bnxt[ni] = *(const bf16x8*)(bbase + ni * 16 * NMID + k0 + 32);
            }
            bf16x8 af[4];
            #pragma unroll
            for (int mi = 0; mi < 4; ++mi) {
                int row = mi * 16 + lr;
                af[mi] = *(const bf16x8*)(smem + ((row * 1024 + (k0 + kg) * 2) ^ ((row & 15) << 4)));
            }
            #pragma unroll
            for (int mi = 0; mi < 4; ++mi)
                #pragma unroll
                for (int ni = 0; ni < 4; ++ni)
                    acc[mi][ni] = __builtin_amdgcn_mfma_f32_16x16x32_bf16(af[mi], bcur[ni], acc[mi][ni], 0, 0, 0);
            if (k0 + 32 < NMID) {
                #pragma unroll
                for (int ni = 0; ni < 4; ++ni) bcur[ni] = bnxt[ni];
            }
        }
    }
    // epilogue 2: bias + permuted store; row pointer hoisted per (mi,j)
    float bv4[4];
    #pragma unroll
    for (int ni = 0; ni < 4; ++ni) bv4[ni] = b2[n0w + ni * 16 + lr];
    #pragma unroll
    for (int mi = 0; mi < 4; ++mi) {
        int row0 = mbase + mi * 16 + rbase;
        #pragma unroll
        for (int j = 0; j < 4; ++j) {
            int row = row0 + j;
            int b = row & 31;
            int node = row >> 5;
            float* orow = out + ((size_t)posmap[node] * NB + b) * NV + n0w + lr;
            #pragma unroll
            for (int ni = 0; ni < 4; ++ni)
                orow[ni * 16] = acc[mi][ni][j] + bv4[ni];
        }
    }
}

extern "C" void kernel_launch(void* const* d_in, const int* in_sizes, int n_in,
                              void* d_out, int out_size, void* d_ws, size_t ws_size,
                              hipStream_t stream) {
    const float* root      = (const float*)d_in[0];
    const float* ann_table = (const float*)d_in[1];
    const float* w1        = (const float*)d_in[2];
    const float* b1        = (const float*)d_in[3];
    const float* w2        = (const float*)d_in[4];
    const float* b2        = (const float*)d_in[5];
    const float* w_ih      = (const float*)d_in[6];
    const float* w_hh      = (const float*)d_in[7];
    const float* b_ih      = (const float*)d_in[8];
    const float* b_hh      = (const float*)d_in[9];
    const int*   ann_ids   = (const int*)d_in[10];

    uint8_t* ws = (uint8_t*)d_ws;
    unsigned short* whh_b = (unsigned short*)ws; ws += (size_t)NG * NH * 2;
    unsigned short* w1_b  = (unsigned short*)ws; ws += (size_t)NMID * NH * 2;
    unsigned short* w2_b  = (unsigned short*)ws; ws += (size_t)NV * NMID * 2;
    float* gx_t           = (float*)ws;          ws += (size_t)NB * NG * 4;
    int* posmap           = (int*)ws;            ws += (size_t)NNODES * 4;
    unsigned short* hid_b = (unsigned short*)ws; ws += (size_t)NNODES * NB * NH * 2;

    prep_all<<<1024, 256, 0, stream>>>(root, ann_table, ann_ids, w_ih, b_ih,
                                       w_hh, w1, w2, whh_b, w1_b, w2_b,
                                       gx_t, posmap, hid_b);

    int start = 0, cnt = 1;
    for (int l = 0; l < NDEPTH; ++l) {
        int child_start = start + cnt;
        if (cnt >= 729) {
            gru_level<4><<<dim3((cnt + 3) / 4, 6), 512, 0, stream>>>(
                hid_b, hid_b, whh_b, b_hh, gx_t, start, child_start, cnt);
        } else if (cnt >= 128) {
            gru_level<2><<<dim3((cnt + 1) / 2, 6), 512, 0, stream>>>(
                hid_b, hid_b, whh_b, b_hh, gx_t, start, child_start, cnt);
        } else {
            gru_level<1><<<dim3(cnt, 6), 512, 0, stream>>>(
                hid_b, hid_b, whh_b, b_hh, gx_t, start, child_start, cnt);
        }
        start = child_start; cnt *= 3;
    }
    head_fused<<<MROWS / HM, 512, 0, stream>>>(hid_b, w1_b, b1, w2_b, b2, posmap, (float*)d_out);
}